// Round 3
// baseline (5335.976 us; speedup 1.0000x reference)
//
#include <hip/hip_runtime.h>
#include <math.h>

#define MUP 0.35f       // 1.4/sqrt(16)
#define SCALE 0.125f    // 1/sqrt(64)
#define EPS 1e-5f

// workspace float offsets
#define WS_HA    0          // h at layer entry [4][1024]
#define WS_HB    4096       // h after attn-residual input side [4][1024]
#define WS_YMLP  8192       // [4][1024] (atomic accum)
#define WS_YO    12288      // [4][1024] (atomic accum)
#define WS_QKVP  16384      // [16][4][2048] partials (aliased with GUP)
#define WS_GUP   16384      // [2][8][4][4096] partials
#define WS_OPART 278528     // [4][8][16][132]
#define WS_BARI  346112     // 32 ints barrier state

// d_out float offsets
#define OUT_NK  4096
#define OUT_NV  (4096 + 16*4*8*2049*64)
#define OUT_SC  (4096 + 2*16*4*8*2049*64)

__device__ __forceinline__ float wsum64(float v) {
    v += __shfl_xor(v, 32); v += __shfl_xor(v, 16); v += __shfl_xor(v, 8);
    v += __shfl_xor(v, 4);  v += __shfl_xor(v, 2);  v += __shfl_xor(v, 1);
    return v;
}

__device__ __forceinline__ void fma4(float4& a, float s, const float4 w) {
    a.x = fmaf(s, w.x, a.x); a.y = fmaf(s, w.y, a.y);
    a.z = fmaf(s, w.z, a.z); a.w = fmaf(s, w.w, a.w);
}

struct SmemGemv {
    float xs[4][128];          // staged x (b-major)
    float4 red[4][64][4];      // cross-wave reduce
    float sred[4][4];          // [wave][b]
};
struct SmemAttn {
    float sc[2][132];
    float wm[2][4];
    float oacc[2][4][64];
    float wl[2][4];
};
union Smem { SmemGemv g; SmemAttn a; };

// two-level grid barrier: B[0]=generation, B[1]=root count, B[2..17]=group counts
__device__ __forceinline__ void gbar(int* B) {
    __syncthreads();
    if (threadIdx.x == 0) {
        int gen = __hip_atomic_load(&B[0], __ATOMIC_RELAXED, __HIP_MEMORY_SCOPE_AGENT);
        int grp = (int)(blockIdx.x >> 5);
        if (__hip_atomic_fetch_add(&B[2 + grp], 1, __ATOMIC_ACQ_REL, __HIP_MEMORY_SCOPE_AGENT) == 31) {
            __hip_atomic_store(&B[2 + grp], 0, __ATOMIC_RELAXED, __HIP_MEMORY_SCOPE_AGENT);
            if (__hip_atomic_fetch_add(&B[1], 1, __ATOMIC_ACQ_REL, __HIP_MEMORY_SCOPE_AGENT) == 15) {
                __hip_atomic_store(&B[1], 0, __ATOMIC_RELAXED, __HIP_MEMORY_SCOPE_AGENT);
                __hip_atomic_fetch_add(&B[0], 1, __ATOMIC_RELEASE, __HIP_MEMORY_SCOPE_AGENT);
            }
        }
        while (__hip_atomic_load(&B[0], __ATOMIC_RELAXED, __HIP_MEMORY_SCOPE_AGENT) == gen)
            __builtin_amdgcn_s_sleep(16);
        __threadfence();   // acquire: invalidate stale L1/L2 lines
    }
    __syncthreads();
}

__global__ __launch_bounds__(256) void k_init(const float* __restrict__ emb,
                                              const int* __restrict__ cl,
                                              float* __restrict__ ws,
                                              float* __restrict__ out) {
    int tid = threadIdx.x;
    float4* ws4 = (float4*)ws;
    float4 z = {0.f, 0.f, 0.f, 0.f};
    if (blockIdx.x == 0) {
        const float4* e4 = (const float4*)emb;
        #pragma unroll
        for (int k = 0; k < 4; ++k) ws4[(WS_HA >> 2) + k * 256 + tid] = e4[k * 256 + tid];
        if (tid == 0) out[OUT_SC] = (float)(cl[0] + 1);
    } else if (blockIdx.x == 1) {
        #pragma unroll
        for (int k = 0; k < 4; ++k) ws4[(WS_YMLP >> 2) + k * 256 + tid] = z;
    } else if (blockIdx.x == 2) {
        #pragma unroll
        for (int k = 0; k < 4; ++k) ws4[(WS_YO >> 2) + k * 256 + tid] = z;
    } else {
        if (tid < 32) ((int*)(ws + WS_BARI))[tid] = 0;
    }
}

__global__ __launch_bounds__(256, 2) void k_main(
    const float* __restrict__ kc, const float* __restrict__ vc,
    const float* __restrict__ ln1, const float* __restrict__ ln2,
    const float* __restrict__ nrmw,
    const float* __restrict__ wq, const float* __restrict__ wk,
    const float* __restrict__ wv, const float* __restrict__ wo,
    const float* __restrict__ wg, const float* __restrict__ wu,
    const float* __restrict__ wd, const int* __restrict__ cl,
    float* __restrict__ ws, float* __restrict__ nk, float* __restrict__ nv,
    float* __restrict__ out)
{
    __shared__ Smem sm;
    const int bid = blockIdx.x, tid = threadIdx.x;
    const int w = tid >> 6, lane = tid & 63;
    int* B = (int*)(ws + WS_BARI);
    float4* ws4 = (float4*)ws;
    float4* HA4   = ws4 + (WS_HA >> 2);
    float4* HB4   = ws4 + (WS_HB >> 2);
    float4* YMLP4 = ws4 + (WS_YMLP >> 2);
    float4* YO4   = ws4 + (WS_YO >> 2);
    float4* QKVP4 = ws4 + (WS_QKVP >> 2);
    float4* GUP4  = ws4 + (WS_GUP >> 2);
    const float4* LN14 = (const float4*)ln1;
    const float4* LN24 = (const float4*)ln2;

    // RoPE per-thread constants (used in attn phase; j = lane&15)
    const float pos = (float)cl[0];
    float cs4[4], sn4[4];
    {
        int j = lane & 15;
        #pragma unroll
        for (int m = 0; m < 4; ++m) {
            float t = (float)(4 * (j & 7) + m);
            float fr = pos * __expf(-t * 0.2878231366242557f);  // ln(1e4)/32
            cs4[m] = cosf(fr); sn4[m] = sinf(fr);
        }
    }

    for (int l = 0; l < 16; ++l) {
        // ================= QKV (fused rms1 recompute) : blocks 0..127 =================
        if (bid < 128) {
            const int s = bid >> 3, xt = bid & 7;
            float4 hn[4]; float rstd[4]; float ss[4];
            #pragma unroll
            for (int b = 0; b < 4; ++b) {
                float4 h = HA4[b * 256 + tid];
                float4 y = YMLP4[b * 256 + tid];
                h.x = fmaf(MUP, y.x, h.x); h.y = fmaf(MUP, y.y, h.y);
                h.z = fmaf(MUP, y.z, h.z); h.w = fmaf(MUP, y.w, h.w);
                hn[b] = h;
                ss[b] = h.x*h.x + h.y*h.y + h.z*h.z + h.w*h.w;
            }
            #pragma unroll
            for (int b = 0; b < 4; ++b) {
                float v = wsum64(ss[b]);
                if (lane == 0) sm.g.sred[w][b] = v;
            }
            __syncthreads();
            #pragma unroll
            for (int b = 0; b < 4; ++b)
                rstd[b] = rsqrtf((sm.g.sred[0][b] + sm.g.sred[1][b] + sm.g.sred[2][b] + sm.g.sred[3][b]) * (1.f/1024.f) + EPS);
            if (bid == 0) {
                #pragma unroll
                for (int b = 0; b < 4; ++b) HB4[b * 256 + tid] = hn[b];
            }
            {
                int tl = tid - s * 16;
                if (tl >= 0 && tl < 16) {
                    float4 g4 = LN14[l * 256 + tid];
                    #pragma unroll
                    for (int b = 0; b < 4; ++b) {
                        float4 xv;
                        xv.x = hn[b].x * rstd[b] * g4.x;
                        xv.y = hn[b].y * rstd[b] * g4.y;
                        xv.z = hn[b].z * rstd[b] * g4.z;
                        xv.w = hn[b].w * rstd[b] * g4.w;
                        ((float4*)sm.g.xs[b])[tl] = xv;
                    }
                }
            }
            __syncthreads();
            const float* Wp; int nc; int c;
            if (xt < 4)      { Wp = wq + (size_t)l * 1024 * 1024; nc = 1024; c = xt * 256 + lane * 4; }
            else if (xt < 6) { Wp = wk + (size_t)l * 1024 * 512;  nc = 512;  c = (xt - 4) * 256 + lane * 4; }
            else             { Wp = wv + (size_t)l * 1024 * 512;  nc = 512;  c = (xt - 6) * 256 + lane * 4; }
            const float4* W4 = (const float4*)(Wp + c);
            const size_t nc4 = (size_t)(nc >> 2);
            float4 a0 = {0,0,0,0}, a1 = a0, a2 = a0, a3 = a0;
            #pragma unroll 8
            for (int rr = 0; rr < 16; ++rr) {
                int r = w * 16 + rr;
                float4 wv4 = W4[(size_t)(s * 64 + r) * nc4];
                fma4(a0, sm.g.xs[0][r], wv4); fma4(a1, sm.g.xs[1][r], wv4);
                fma4(a2, sm.g.xs[2][r], wv4); fma4(a3, sm.g.xs[3][r], wv4);
            }
            sm.g.red[w][lane][0] = a0; sm.g.red[w][lane][1] = a1;
            sm.g.red[w][lane][2] = a2; sm.g.red[w][lane][3] = a3;
            __syncthreads();
            if (w == 0) {
                #pragma unroll
                for (int b = 0; b < 4; ++b) {
                    float4 s0v = sm.g.red[0][lane][b], s1v = sm.g.red[1][lane][b],
                           s2v = sm.g.red[2][lane][b], s3v = sm.g.red[3][lane][b];
                    s0v.x += s1v.x + s2v.x + s3v.x; s0v.y += s1v.y + s2v.y + s3v.y;
                    s0v.z += s1v.z + s2v.z + s3v.z; s0v.w += s1v.w + s2v.w + s3v.w;
                    QKVP4[(size_t)(s * 4 + b) * 512 + xt * 64 + lane] = s0v;
                }
            }
        }
        gbar(B);

        // ================= ATTN (flash-decode + fused cache copy) : all 512 =================
        {
            const int b = bid >> 7, rem = bid & 127, kvh = rem >> 4, c = rem & 15;
            const int s0 = c * 128;
            const int sub = lane >> 4, j = lane & 15;
            const float sgn = (j < 8) ? -1.f : 1.f;

            float4 q0 = {0,0,0,0}, q1 = {0,0,0,0};
            #pragma unroll
            for (int sp = 0; sp < 16; ++sp) {
                const float4* qp = QKVP4 + (size_t)(sp * 4 + b) * 512 + kvh * 32;
                float4 t0 = qp[j], t1 = qp[16 + j];
                q0.x += t0.x; q0.y += t0.y; q0.z += t0.z; q0.w += t0.w;
                q1.x += t1.x; q1.y += t1.y; q1.z += t1.z; q1.w += t1.w;
            }
            {
                float4 q0p, q1p;
                q0p.x = __shfl_xor(q0.x, 8); q0p.y = __shfl_xor(q0.y, 8);
                q0p.z = __shfl_xor(q0.z, 8); q0p.w = __shfl_xor(q0.w, 8);
                q1p.x = __shfl_xor(q1.x, 8); q1p.y = __shfl_xor(q1.y, 8);
                q1p.z = __shfl_xor(q1.z, 8); q1p.w = __shfl_xor(q1.w, 8);
                q0.x = q0.x * cs4[0] + sgn * q0p.x * sn4[0];
                q0.y = q0.y * cs4[1] + sgn * q0p.y * sn4[1];
                q0.z = q0.z * cs4[2] + sgn * q0p.z * sn4[2];
                q0.w = q0.w * cs4[3] + sgn * q0p.w * sn4[3];
                q1.x = q1.x * cs4[0] + sgn * q1p.x * sn4[0];
                q1.y = q1.y * cs4[1] + sgn * q1p.y * sn4[1];
                q1.z = q1.z * cs4[2] + sgn * q1p.z * sn4[2];
                q1.w = q1.w * cs4[3] + sgn * q1p.w * sn4[3];
            }

            size_t cbase = (size_t)((l * 4 + b) * 8 + kvh);
            const float4* kc4 = (const float4*)kc + cbase * 2048 * 16;
            float4* nk4 = (float4*)nk + cbase * 2049 * 16;
            float m0 = -1e30f, m1 = -1e30f;
            const int rbase = s0 + w * 32;
            #pragma unroll 4
            for (int i = 0; i < 8; ++i) {
                int r = rbase + i * 4 + sub;
                float4 kv = kc4[(size_t)r * 16 + j];
                nk4[(size_t)r * 16 + j] = kv;
                float d0 = kv.x*q0.x + kv.y*q0.y + kv.z*q0.z + kv.w*q0.w;
                float d1 = kv.x*q1.x + kv.y*q1.y + kv.z*q1.z + kv.w*q1.w;
                d0 += __shfl_xor(d0, 1); d0 += __shfl_xor(d0, 2);
                d0 += __shfl_xor(d0, 4); d0 += __shfl_xor(d0, 8);
                d1 += __shfl_xor(d1, 1); d1 += __shfl_xor(d1, 2);
                d1 += __shfl_xor(d1, 4); d1 += __shfl_xor(d1, 8);
                d0 *= SCALE; d1 *= SCALE;
                if (j == 0) { sm.a.sc[0][r - s0] = d0; sm.a.sc[1][r - s0] = d1; }
                m0 = fmaxf(m0, d0); m1 = fmaxf(m1, d1);
            }
            if (c == 15 && w == 0 && sub == 0) {
                float4 kv = {0,0,0,0};
                #pragma unroll
                for (int sp = 0; sp < 16; ++sp) {
                    float4 t0 = QKVP4[(size_t)(sp * 4 + b) * 512 + 256 + kvh * 16 + j];
                    kv.x += t0.x; kv.y += t0.y; kv.z += t0.z; kv.w += t0.w;
                }
                float4 kp;
                kp.x = __shfl_xor(kv.x, 8); kp.y = __shfl_xor(kv.y, 8);
                kp.z = __shfl_xor(kv.z, 8); kp.w = __shfl_xor(kv.w, 8);
                kv.x = kv.x * cs4[0] + sgn * kp.x * sn4[0];
                kv.y = kv.y * cs4[1] + sgn * kp.y * sn4[1];
                kv.z = kv.z * cs4[2] + sgn * kp.z * sn4[2];
                kv.w = kv.w * cs4[3] + sgn * kp.w * sn4[3];
                nk4[(size_t)2048 * 16 + j] = kv;
                float d0 = kv.x*q0.x + kv.y*q0.y + kv.z*q0.z + kv.w*q0.w;
                float d1 = kv.x*q1.x + kv.y*q1.y + kv.z*q1.z + kv.w*q1.w;
                d0 += __shfl_xor(d0, 1); d0 += __shfl_xor(d0, 2);
                d0 += __shfl_xor(d0, 4); d0 += __shfl_xor(d0, 8);
                d1 += __shfl_xor(d1, 1); d1 += __shfl_xor(d1, 2);
                d1 += __shfl_xor(d1, 4); d1 += __shfl_xor(d1, 8);
                d0 *= SCALE; d1 *= SCALE;
                if (j == 0) { sm.a.sc[0][128] = d0; sm.a.sc[1][128] = d1; }
                m0 = fmaxf(m0, d0); m1 = fmaxf(m1, d1);
            }
            m0 = fmaxf(m0, __shfl_xor(m0, 16)); m0 = fmaxf(m0, __shfl_xor(m0, 32));
            m1 = fmaxf(m1, __shfl_xor(m1, 16)); m1 = fmaxf(m1, __shfl_xor(m1, 32));
            if (lane == 0) { sm.a.wm[0][w] = m0; sm.a.wm[1][w] = m1; }
            __syncthreads();
            float M0 = fmaxf(fmaxf(sm.a.wm[0][0], sm.a.wm[0][1]), fmaxf(sm.a.wm[0][2], sm.a.wm[0][3]));
            float M1 = fmaxf(fmaxf(sm.a.wm[1][0], sm.a.wm[1][1]), fmaxf(sm.a.wm[1][2], sm.a.wm[1][3]));

            const float4* vc4 = (const float4*)vc + cbase * 2048 * 16;
            float4* nv4 = (float4*)nv + cbase * 2049 * 16;
            float4 o0 = {0,0,0,0}, o1 = {0,0,0,0};
            float l0 = 0.f, l1 = 0.f;
            #pragma unroll 4
            for (int i = 0; i < 8; ++i) {
                int r = rbase + i * 4 + sub;
                float4 vv = vc4[(size_t)r * 16 + j];
                nv4[(size_t)r * 16 + j] = vv;
                float p0 = __expf(sm.a.sc[0][r - s0] - M0);
                float p1 = __expf(sm.a.sc[1][r - s0] - M1);
                fma4(o0, p0, vv); fma4(o1, p1, vv);
                l0 += p0; l1 += p1;
            }
            if (c == 15 && w == 0 && sub == 0) {
                float4 vv = {0,0,0,0};
                #pragma unroll
                for (int sp = 0; sp < 16; ++sp) {
                    float4 t0 = QKVP4[(size_t)(sp * 4 + b) * 512 + 384 + kvh * 16 + j];
                    vv.x += t0.x; vv.y += t0.y; vv.z += t0.z; vv.w += t0.w;
                }
                nv4[(size_t)2048 * 16 + j] = vv;
                float p0 = __expf(sm.a.sc[0][128] - M0);
                float p1 = __expf(sm.a.sc[1][128] - M1);
                fma4(o0, p0, vv); fma4(o1, p1, vv);
                l0 += p0; l1 += p1;
            }
            o0.x += __shfl_xor(o0.x, 16); o0.x += __shfl_xor(o0.x, 32);
            o0.y += __shfl_xor(o0.y, 16); o0.y += __shfl_xor(o0.y, 32);
            o0.z += __shfl_xor(o0.z, 16); o0.z += __shfl_xor(o0.z, 32);
            o0.w += __shfl_xor(o0.w, 16); o0.w += __shfl_xor(o0.w, 32);
            o1.x += __shfl_xor(o1.x, 16); o1.x += __shfl_xor(o1.x, 32);
            o1.y += __shfl_xor(o1.y, 16); o1.y += __shfl_xor(o1.y, 32);
            o1.z += __shfl_xor(o1.z, 16); o1.z += __shfl_xor(o1.z, 32);
            o1.w += __shfl_xor(o1.w, 16); o1.w += __shfl_xor(o1.w, 32);
            l0 += __shfl_xor(l0, 16); l0 += __shfl_xor(l0, 32);
            l1 += __shfl_xor(l1, 16); l1 += __shfl_xor(l1, 32);
            if (sub == 0) {
                sm.a.oacc[0][w][4*j+0] = o0.x; sm.a.oacc[0][w][4*j+1] = o0.y;
                sm.a.oacc[0][w][4*j+2] = o0.z; sm.a.oacc[0][w][4*j+3] = o0.w;
                sm.a.oacc[1][w][4*j+0] = o1.x; sm.a.oacc[1][w][4*j+1] = o1.y;
                sm.a.oacc[1][w][4*j+2] = o1.z; sm.a.oacc[1][w][4*j+3] = o1.w;
            }
            if (lane == 0) { sm.a.wl[0][w] = l0; sm.a.wl[1][w] = l1; }
            __syncthreads();
            int pbase = WS_OPART + ((b * 8 + kvh) * 16 + c) * 132;
            if (tid < 128) {
                int h = tid >> 6, d = tid & 63;
                ws[pbase + h * 64 + d] = sm.a.oacc[h][0][d] + sm.a.oacc[h][1][d]
                                       + sm.a.oacc[h][2][d] + sm.a.oacc[h][3][d];
            } else if (tid == 128) {
                ws[pbase + 128] = M0;
                ws[pbase + 129] = sm.a.wl[0][0] + sm.a.wl[0][1] + sm.a.wl[0][2] + sm.a.wl[0][3];
                ws[pbase + 130] = M1;
                ws[pbase + 131] = sm.a.wl[1][0] + sm.a.wl[1][1] + sm.a.wl[1][2] + sm.a.wl[1][3];
            }
        }
        gbar(B);

        // ================= OPROJ (chunk-reduce fused) : blocks 0..127 ; 128..131 zero y_mlp =================
        if (bid < 128) {
            const int xt = bid & 3, s = bid >> 2;   // s: 0..31, 32 rows each
            if (tid < 128) {
                const int bb = tid >> 5, rr = tid & 31;
                const int r = s * 32 + rr;
                const int kvh = r >> 7, g = (r >> 6) & 1, d = r & 63;
                const float* bp = ws + WS_OPART + (size_t)((bb * 8 + kvh) * 16) * 132;
                float m = -1e30f;
                #pragma unroll
                for (int cc = 0; cc < 16; ++cc)
                    m = fmaxf(m, bp[cc * 132 + 128 + 2 * g]);
                float lt = 0.f, ot = 0.f;
                #pragma unroll
                for (int cc = 0; cc < 16; ++cc) {
                    float f = __expf(bp[cc * 132 + 128 + 2 * g] - m);
                    lt += bp[cc * 132 + 129 + 2 * g] * f;
                    ot += bp[cc * 132 + g * 64 + d] * f;
                }
                sm.g.xs[bb][rr] = ot / lt;
            }
            __syncthreads();
            const float4* W4 = (const float4*)(wo + (size_t)l * 1024 * 1024 + xt * 256 + lane * 4);
            float4 a0 = {0,0,0,0}, a1 = a0, a2 = a0, a3 = a0;
            #pragma unroll
            for (int rr = 0; rr < 8; ++rr) {
                int r = w * 8 + rr;
                float4 wv4 = W4[(size_t)(s * 32 + r) * 256];
                fma4(a0, sm.g.xs[0][r], wv4); fma4(a1, sm.g.xs[1][r], wv4);
                fma4(a2, sm.g.xs[2][r], wv4); fma4(a3, sm.g.xs[3][r], wv4);
            }
            sm.g.red[w][lane][0] = a0; sm.g.red[w][lane][1] = a1;
            sm.g.red[w][lane][2] = a2; sm.g.red[w][lane][3] = a3;
            __syncthreads();
            if (w == 0) {
                int c = xt * 256 + lane * 4;
                #pragma unroll
                for (int b = 0; b < 4; ++b) {
                    float4 s0v = sm.g.red[0][lane][b], s1v = sm.g.red[1][lane][b],
                           s2v = sm.g.red[2][lane][b], s3v = sm.g.red[3][lane][b];
                    s0v.x += s1v.x + s2v.x + s3v.x; s0v.y += s1v.y + s2v.y + s3v.y;
                    s0v.z += s1v.z + s2v.z + s3v.z; s0v.w += s1v.w + s2v.w + s3v.w;
                    atomicAdd(&ws[WS_YO + b * 1024 + c + 0], s0v.x);
                    atomicAdd(&ws[WS_YO + b * 1024 + c + 1], s0v.y);
                    atomicAdd(&ws[WS_YO + b * 1024 + c + 2], s0v.z);
                    atomicAdd(&ws[WS_YO + b * 1024 + c + 3], s0v.w);
                }
            }
        } else if (bid >= 128 && bid < 132) {
            float4 z = {0,0,0,0};
            YMLP4[(bid - 128) * 256 + tid] = z;
        }
        gbar(B);

        // ================= GATEUP (fused rms2 recompute) : blocks 0..255 =================
        if (bid < 256) {
            const int t16 = bid & 15, mat = (bid >> 4) & 1, s = bid >> 5;  // s: 0..7, 128 rows
            float4 hn[4]; float rstd[4]; float ss[4];
            #pragma unroll
            for (int b = 0; b < 4; ++b) {
                float4 h = HB4[b * 256 + tid];
                float4 y = YO4[b * 256 + tid];
                h.x = fmaf(MUP, y.x, h.x); h.y = fmaf(MUP, y.y, h.y);
                h.z = fmaf(MUP, y.z, h.z); h.w = fmaf(MUP, y.w, h.w);
                hn[b] = h;
                ss[b] = h.x*h.x + h.y*h.y + h.z*h.z + h.w*h.w;
            }
            #pragma unroll
            for (int b = 0; b < 4; ++b) {
                float v = wsum64(ss[b]);
                if (lane == 0) sm.g.sred[w][b] = v;
            }
            __syncthreads();
            #pragma unroll
            for (int b = 0; b < 4; ++b)
                rstd[b] = rsqrtf((sm.g.sred[0][b] + sm.g.sred[1][b] + sm.g.sred[2][b] + sm.g.sred[3][b]) * (1.f/1024.f) + EPS);
            if (bid == 0) {
                #pragma unroll
                for (int b = 0; b < 4; ++b) HA4[b * 256 + tid] = hn[b];
            }
            {
                int tl = tid - s * 32;
                if (tl >= 0 && tl < 32) {
                    float4 g4 = LN24[l * 256 + tid];
                    #pragma unroll
                    for (int b = 0; b < 4; ++b) {
                        float4 xv;
                        xv.x = hn[b].x * rstd[b] * g4.x;
                        xv.y = hn[b].y * rstd[b] * g4.y;
                        xv.z = hn[b].z * rstd[b] * g4.z;
                        xv.w = hn[b].w * rstd[b] * g4.w;
                        ((float4*)sm.g.xs[b])[tl] = xv;
                    }
                }
            }
            __syncthreads();
            const float* Wm = (mat ? wu : wg) + (size_t)l * 1024 * 4096;
            const float4* W4 = (const float4*)(Wm + t16 * 256 + lane * 4);
            float4 a0 = {0,0,0,0}, a1 = a0, a2 = a0, a3 = a0;
            #pragma unroll 8
            for (int rr = 0; rr < 32; ++rr) {
                int r = w * 32 + rr;
                float4 wv4 = W4[(size_t)(s * 128 + r) * 1024];
                fma4(a0, sm.g.xs[0][r], wv4); fma4(a1, sm.g.xs[1][r], wv4);
                fma4(a2, sm.g.xs[2][r], wv4); fma4(a3, sm.g.xs[3][r], wv4);
            }
            sm.g.red[w][lane][0] = a0; sm.g.red[w][lane][1] = a1;
            sm.g.red[w][lane][2] = a2; sm.g.red[w][lane][3] = a3;
            __syncthreads();
            if (w == 0) {
                #pragma unroll
                for (int b = 0; b < 4; ++b) {
                    float4 s0v = sm.g.red[0][lane][b], s1v = sm.g.red[1][lane][b],
                           s2v = sm.g.red[2][lane][b], s3v = sm.g.red[3][lane][b];
                    s0v.x += s1v.x + s2v.x + s3v.x; s0v.y += s1v.y + s2v.y + s3v.y;
                    s0v.z += s1v.z + s2v.z + s3v.z; s0v.w += s1v.w + s2v.w + s3v.w;
                    GUP4[(size_t)((mat * 8 + s) * 4 + b) * 1024 + t16 * 64 + lane] = s0v;
                }
            }
        }
        gbar(B);

        // ================= DOWN : blocks 0..127 ; 128..131 zero y_o =================
        if (bid < 128) {
            const int xt = bid & 3, s = bid >> 2;   // s: 0..31, 128 f-rows
            if (tid < 128) {
                const int bb = tid >> 5, i = tid & 31;
                const int f4 = s * 32 + i;
                float4 g = {0,0,0,0}, u = {0,0,0,0};
                #pragma unroll
                for (int sp = 0; sp < 8; ++sp) {
                    float4 gv = GUP4[(size_t)(sp * 4 + bb) * 1024 + f4];
                    float4 uv = GUP4[(size_t)((8 + sp) * 4 + bb) * 1024 + f4];
                    g.x += gv.x; g.y += gv.y; g.z += gv.z; g.w += gv.w;
                    u.x += uv.x; u.y += uv.y; u.z += uv.z; u.w += uv.w;
                }
                float4 t;
                t.x = (g.x / (1.f + __expf(-g.x))) * u.x;
                t.y = (g.y / (1.f + __expf(-g.y))) * u.y;
                t.z = (g.z / (1.f + __expf(-g.z))) * u.z;
                t.w = (g.w / (1.f + __expf(-g.w))) * u.w;
                ((float4*)sm.g.xs[bb])[i] = t;
            }
            __syncthreads();
            const float4* W4 = (const float4*)(wd + (size_t)l * 4096 * 1024 + xt * 256 + lane * 4);
            float4 a0 = {0,0,0,0}, a1 = a0, a2 = a0, a3 = a0;
            #pragma unroll 8
            for (int rr = 0; rr < 32; ++rr) {
                int r = w * 32 + rr;
                float4 wv4 = W4[(size_t)(s * 128 + r) * 256];
                fma4(a0, sm.g.xs[0][r], wv4); fma4(a1, sm.g.xs[1][r], wv4);
                fma4(a2, sm.g.xs[2][r], wv4); fma4(a3, sm.g.xs[3][r], wv4);
            }
            sm.g.red[w][lane][0] = a0; sm.g.red[w][lane][1] = a1;
            sm.g.red[w][lane][2] = a2; sm.g.red[w][lane][3] = a3;
            __syncthreads();
            if (w == 0) {
                int c = xt * 256 + lane * 4;
                #pragma unroll
                for (int b = 0; b < 4; ++b) {
                    float4 s0v = sm.g.red[0][lane][b], s1v = sm.g.red[1][lane][b],
                           s2v = sm.g.red[2][lane][b], s3v = sm.g.red[3][lane][b];
                    s0v.x += s1v.x + s2v.x + s3v.x; s0v.y += s1v.y + s2v.y + s3v.y;
                    s0v.z += s1v.z + s2v.z + s3v.z; s0v.w += s1v.w + s2v.w + s3v.w;
                    atomicAdd(&ws[WS_YMLP + b * 1024 + c + 0], s0v.x);
                    atomicAdd(&ws[WS_YMLP + b * 1024 + c + 1], s0v.y);
                    atomicAdd(&ws[WS_YMLP + b * 1024 + c + 2], s0v.z);
                    atomicAdd(&ws[WS_YMLP + b * 1024 + c + 3], s0v.w);
                }
            }
        } else if (bid >= 128 && bid < 132) {
            float4 z = {0,0,0,0};
            YO4[(bid - 128) * 256 + tid] = z;
        }
        gbar(B);
    }

    // ================= FINAL NORM : blocks 0..3 =================
    if (bid < 4) {
        const int b = bid;
        float4 h = HA4[b * 256 + tid], y = YMLP4[b * 256 + tid];
        h.x = fmaf(MUP, y.x, h.x); h.y = fmaf(MUP, y.y, h.y);
        h.z = fmaf(MUP, y.z, h.z); h.w = fmaf(MUP, y.w, h.w);
        float ssv = h.x*h.x + h.y*h.y + h.z*h.z + h.w*h.w;
        float v = wsum64(ssv);
        if (lane == 0) sm.g.sred[w][0] = v;
        __syncthreads();
        float rstd = rsqrtf((sm.g.sred[0][0] + sm.g.sred[1][0] + sm.g.sred[2][0] + sm.g.sred[3][0]) * (1.f/1024.f) + EPS);
        float4 g4 = ((const float4*)nrmw)[tid];
        float4 o;
        o.x = h.x * rstd * g4.x; o.y = h.y * rstd * g4.y;
        o.z = h.z * rstd * g4.z; o.w = h.w * rstd * g4.w;
        ((float4*)out)[b * 256 + tid] = o;
    }
}

extern "C" void kernel_launch(void* const* d_in, const int* in_sizes, int n_in,
                              void* d_out, int out_size, void* d_ws, size_t ws_size,
                              hipStream_t stream) {
    const float* emb  = (const float*)d_in[0];
    const float* kc   = (const float*)d_in[1];
    const float* vc   = (const float*)d_in[2];
    const float* ln1  = (const float*)d_in[3];
    const float* ln2  = (const float*)d_in[4];
    const float* nrmw = (const float*)d_in[5];
    const float* wq   = (const float*)d_in[6];
    const float* wk   = (const float*)d_in[7];
    const float* wv   = (const float*)d_in[8];
    const float* wo   = (const float*)d_in[9];
    const float* wg   = (const float*)d_in[10];
    const float* wu   = (const float*)d_in[11];
    const float* wd   = (const float*)d_in[12];
    const int*   cl   = (const int*)d_in[13];

    float* out = (float*)d_out;
    float* ws  = (float*)d_ws;
    float* nk  = out + OUT_NK;
    float* nv  = out + OUT_NV;

    k_init<<<4, 256, 0, stream>>>(emb, cl, ws, out);
    k_main<<<512, 256, 0, stream>>>(kc, vc, ln1, ln2, nrmw, wq, wk, wv, wo,
                                    wg, wu, wd, cl, ws, nk, nv, out);
}

// Round 4
// 1064.720 us; speedup vs baseline: 5.0116x; 5.0116x over previous
//
#include <hip/hip_runtime.h>
#include <math.h>

#define MUP 0.35f       // 1.4/sqrt(16)
#define SCALE 0.125f    // 1/sqrt(64)
#define EPS 1e-5f

// workspace float offsets
#define WS_HA    0          // [4][1024] h at layer entry
#define WS_HB    4096       // [4][1024] h after attn residual
#define WS_YMLP  8192       // [4][1024] atomic accum (zeroed by k_c spares)
#define WS_YO    12288      // [4][1024] atomic accum (zeroed by k_a spares)
#define WS_QKVP  16384      // [32][4][2048] qkv k-split partials (aliased w/ GUP)
#define WS_GUP   16384      // [2][8][4][4096] gate/up partials (disjoint lifetime)
#define WS_OPART 278528     // [4][8][16][132] attn chunk partials

// d_out float offsets
#define OUT_NK  4096
#define OUT_NV  (4096 + 16*4*8*2049*64)
#define OUT_SC  (4096 + 2*16*4*8*2049*64)

__device__ __forceinline__ float wsum64(float v) {
    v += __shfl_xor(v, 32); v += __shfl_xor(v, 16); v += __shfl_xor(v, 8);
    v += __shfl_xor(v, 4);  v += __shfl_xor(v, 2);  v += __shfl_xor(v, 1);
    return v;
}

__device__ __forceinline__ void fma4(float4& a, float s, const float4 w) {
    a.x = fmaf(s, w.x, a.x); a.y = fmaf(s, w.y, a.y);
    a.z = fmaf(s, w.z, a.z); a.w = fmaf(s, w.w, a.w);
}

__global__ __launch_bounds__(256) void k_init(const float* __restrict__ emb,
                                              const int* __restrict__ cl,
                                              float* __restrict__ ws,
                                              float* __restrict__ out) {
    int tid = threadIdx.x;
    float4* ws4 = (float4*)ws;
    float4 z = {0.f, 0.f, 0.f, 0.f};
    if (blockIdx.x == 0) {
        const float4* e4 = (const float4*)emb;
        #pragma unroll
        for (int k = 0; k < 4; ++k) ws4[(WS_HA >> 2) + k * 256 + tid] = e4[k * 256 + tid];
        if (tid == 0) out[OUT_SC] = (float)(cl[0] + 1);
    } else if (blockIdx.x == 1) {
        #pragma unroll
        for (int k = 0; k < 4; ++k) ws4[(WS_YMLP >> 2) + k * 256 + tid] = z;
    } else {
        #pragma unroll
        for (int k = 0; k < 4; ++k) ws4[(WS_YO >> 2) + k * 256 + tid] = z;
    }
}

// ===== A: rms1 recompute + QKV GEMV (k-split partials). grid 260, block 256 =====
__global__ __launch_bounds__(256) void k_a(const float* __restrict__ ln1,
                                           const float* __restrict__ wq,
                                           const float* __restrict__ wk,
                                           const float* __restrict__ wv,
                                           float* __restrict__ ws, int l) {
    float4* ws4 = (float4*)ws;
    int tid = threadIdx.x, w = tid >> 6, lane = tid & 63;
    if (blockIdx.x >= 256) {            // zero YO
        float4 z = {0,0,0,0};
        ws4[(WS_YO >> 2) + (blockIdx.x - 256) * 256 + tid] = z;
        return;
    }
    __shared__ float xs[4][32];
    __shared__ float4 red[4][64][4];
    __shared__ float sred[4][4];
    const int s = blockIdx.x >> 3, xt = blockIdx.x & 7;

    float4 hn[4]; float ss[4];
    #pragma unroll
    for (int b = 0; b < 4; ++b) {
        float4 h = ws4[(WS_HA >> 2) + b * 256 + tid];
        float4 y = ws4[(WS_YMLP >> 2) + b * 256 + tid];
        h.x = fmaf(MUP, y.x, h.x); h.y = fmaf(MUP, y.y, h.y);
        h.z = fmaf(MUP, y.z, h.z); h.w = fmaf(MUP, y.w, h.w);
        hn[b] = h;
        ss[b] = h.x*h.x + h.y*h.y + h.z*h.z + h.w*h.w;
    }
    #pragma unroll
    for (int b = 0; b < 4; ++b) {
        float v = wsum64(ss[b]);
        if (lane == 0) sred[w][b] = v;
    }
    __syncthreads();
    float rstd[4];
    #pragma unroll
    for (int b = 0; b < 4; ++b)
        rstd[b] = rsqrtf((sred[0][b] + sred[1][b] + sred[2][b] + sred[3][b]) * (1.f/1024.f) + EPS);
    if (blockIdx.x == 0) {
        #pragma unroll
        for (int b = 0; b < 4; ++b) ws4[(WS_HB >> 2) + b * 256 + tid] = hn[b];
    }
    {
        int tl = tid - s * 8;
        if (tl >= 0 && tl < 8) {
            float4 g4 = ((const float4*)ln1)[l * 256 + tid];
            #pragma unroll
            for (int b = 0; b < 4; ++b) {
                float4 xv;
                xv.x = hn[b].x * rstd[b] * g4.x; xv.y = hn[b].y * rstd[b] * g4.y;
                xv.z = hn[b].z * rstd[b] * g4.z; xv.w = hn[b].w * rstd[b] * g4.w;
                ((float4*)xs[b])[tl] = xv;
            }
        }
    }
    __syncthreads();

    const float* Wp; int nc, c;
    if (xt < 4)      { Wp = wq + (size_t)l * 1024 * 1024; nc = 1024; c = xt * 256 + lane * 4; }
    else if (xt < 6) { Wp = wk + (size_t)l * 1024 * 512;  nc = 512;  c = (xt - 4) * 256 + lane * 4; }
    else             { Wp = wv + (size_t)l * 1024 * 512;  nc = 512;  c = (xt - 6) * 256 + lane * 4; }
    const float4* W4 = (const float4*)(Wp + c);
    const size_t nc4 = (size_t)(nc >> 2);
    float4 a0 = {0,0,0,0}, a1 = a0, a2 = a0, a3 = a0;
    #pragma unroll
    for (int rr = 0; rr < 8; ++rr) {
        int r = w * 8 + rr;
        float4 wv4 = W4[(size_t)(s * 32 + r) * nc4];
        fma4(a0, xs[0][r], wv4); fma4(a1, xs[1][r], wv4);
        fma4(a2, xs[2][r], wv4); fma4(a3, xs[3][r], wv4);
    }
    red[w][lane][0] = a0; red[w][lane][1] = a1;
    red[w][lane][2] = a2; red[w][lane][3] = a3;
    __syncthreads();
    if (w == 0) {
        float4* QKVP4 = ws4 + (WS_QKVP >> 2);
        #pragma unroll
        for (int b = 0; b < 4; ++b) {
            float4 s0v = red[0][lane][b], s1v = red[1][lane][b],
                   s2v = red[2][lane][b], s3v = red[3][lane][b];
            s0v.x += s1v.x + s2v.x + s3v.x; s0v.y += s1v.y + s2v.y + s3v.y;
            s0v.z += s1v.z + s2v.z + s3v.z; s0v.w += s1v.w + s2v.w + s3v.w;
            QKVP4[(size_t)(s * 4 + b) * 512 + xt * 64 + lane] = s0v;
        }
    }
}

// ===== B: flash-decode + fused cache copy, V staged in LDS. grid 512 =====
__global__ __launch_bounds__(256) void k_b(const float* __restrict__ kc,
                                           const float* __restrict__ vc,
                                           const int* __restrict__ cl,
                                           float* __restrict__ ws,
                                           float* __restrict__ nk,
                                           float* __restrict__ nv, int l) {
    const int bid = blockIdx.x;
    const int b = bid >> 7, rem = bid & 127, kvh = rem >> 4, c = rem & 15;
    const int s0 = c * 128;
    const int tid = threadIdx.x, w = tid >> 6, lane = tid & 63;
    const int sub = lane >> 4, j = lane & 15;
    float4* ws4 = (float4*)ws;
    const float4* QKVP4 = (const float4*)ws4 + (WS_QKVP >> 2);

    __shared__ float4 vst[128][16];    // 32 KB staged V
    __shared__ float sc[2][132];
    __shared__ float wm[2][4];
    __shared__ float oacc[2][4][64];
    __shared__ float wl[2][4];

    const float pos = (float)cl[0];
    float cs4[4], sn4[4];
    #pragma unroll
    for (int m = 0; m < 4; ++m) {
        float t = (float)(4 * (j & 7) + m);
        float fr = pos * __expf(-t * 0.2878231366242557f);  // ln(1e4)/32
        cs4[m] = cosf(fr); sn4[m] = sinf(fr);
    }
    const float sgn = (j < 8) ? -1.f : 1.f;

    // q reduce over 32 k-split partials + RoPE
    float4 q0 = {0,0,0,0}, q1 = {0,0,0,0};
    #pragma unroll
    for (int sp = 0; sp < 32; ++sp) {
        const float4* qp = QKVP4 + (size_t)(sp * 4 + b) * 512 + kvh * 32;
        float4 t0 = qp[j], t1 = qp[16 + j];
        q0.x += t0.x; q0.y += t0.y; q0.z += t0.z; q0.w += t0.w;
        q1.x += t1.x; q1.y += t1.y; q1.z += t1.z; q1.w += t1.w;
    }
    {
        float4 q0p, q1p;
        q0p.x = __shfl_xor(q0.x, 8); q0p.y = __shfl_xor(q0.y, 8);
        q0p.z = __shfl_xor(q0.z, 8); q0p.w = __shfl_xor(q0.w, 8);
        q1p.x = __shfl_xor(q1.x, 8); q1p.y = __shfl_xor(q1.y, 8);
        q1p.z = __shfl_xor(q1.z, 8); q1p.w = __shfl_xor(q1.w, 8);
        q0.x = q0.x * cs4[0] + sgn * q0p.x * sn4[0];
        q0.y = q0.y * cs4[1] + sgn * q0p.y * sn4[1];
        q0.z = q0.z * cs4[2] + sgn * q0p.z * sn4[2];
        q0.w = q0.w * cs4[3] + sgn * q0p.w * sn4[3];
        q1.x = q1.x * cs4[0] + sgn * q1p.x * sn4[0];
        q1.y = q1.y * cs4[1] + sgn * q1p.y * sn4[1];
        q1.z = q1.z * cs4[2] + sgn * q1p.z * sn4[2];
        q1.w = q1.w * cs4[3] + sgn * q1p.w * sn4[3];
    }

    const size_t cbase = (size_t)((l * 4 + b) * 8 + kvh);
    const float4* kc4 = (const float4*)kc + cbase * 2048 * 16;
    const float4* vc4 = (const float4*)vc + cbase * 2048 * 16;
    float4* nk4 = (float4*)nk + cbase * 2049 * 16;
    float4* nv4 = (float4*)nv + cbase * 2049 * 16;

    float m0 = -1e30f, m1 = -1e30f;
    const int rbase = s0 + w * 32;
    #pragma unroll 4
    for (int i = 0; i < 8; ++i) {
        int r = rbase + i * 4 + sub;
        float4 kv = kc4[(size_t)r * 16 + j];
        float4 vv = vc4[(size_t)r * 16 + j];
        nk4[(size_t)r * 16 + j] = kv;
        nv4[(size_t)r * 16 + j] = vv;
        vst[r - s0][j] = vv;
        float d0 = kv.x*q0.x + kv.y*q0.y + kv.z*q0.z + kv.w*q0.w;
        float d1 = kv.x*q1.x + kv.y*q1.y + kv.z*q1.z + kv.w*q1.w;
        d0 += __shfl_xor(d0, 1); d0 += __shfl_xor(d0, 2);
        d0 += __shfl_xor(d0, 4); d0 += __shfl_xor(d0, 8);
        d1 += __shfl_xor(d1, 1); d1 += __shfl_xor(d1, 2);
        d1 += __shfl_xor(d1, 4); d1 += __shfl_xor(d1, 8);
        d0 *= SCALE; d1 *= SCALE;
        if (j == 0) { sc[0][r - s0] = d0; sc[1][r - s0] = d1; }
        m0 = fmaxf(m0, d0); m1 = fmaxf(m1, d1);
    }
    float4 vnew = {0,0,0,0};
    if (c == 15 && w == 0 && sub == 0) {
        float4 kv = {0,0,0,0};
        #pragma unroll
        for (int sp = 0; sp < 32; ++sp) {
            const float4* pp = QKVP4 + (size_t)(sp * 4 + b) * 512;
            float4 t0 = pp[256 + kvh * 16 + j];
            float4 t1 = pp[384 + kvh * 16 + j];
            kv.x += t0.x; kv.y += t0.y; kv.z += t0.z; kv.w += t0.w;
            vnew.x += t1.x; vnew.y += t1.y; vnew.z += t1.z; vnew.w += t1.w;
        }
        float4 kp;
        kp.x = __shfl_xor(kv.x, 8); kp.y = __shfl_xor(kv.y, 8);
        kp.z = __shfl_xor(kv.z, 8); kp.w = __shfl_xor(kv.w, 8);
        kv.x = kv.x * cs4[0] + sgn * kp.x * sn4[0];
        kv.y = kv.y * cs4[1] + sgn * kp.y * sn4[1];
        kv.z = kv.z * cs4[2] + sgn * kp.z * sn4[2];
        kv.w = kv.w * cs4[3] + sgn * kp.w * sn4[3];
        nk4[(size_t)2048 * 16 + j] = kv;
        nv4[(size_t)2048 * 16 + j] = vnew;
        float d0 = kv.x*q0.x + kv.y*q0.y + kv.z*q0.z + kv.w*q0.w;
        float d1 = kv.x*q1.x + kv.y*q1.y + kv.z*q1.z + kv.w*q1.w;
        d0 += __shfl_xor(d0, 1); d0 += __shfl_xor(d0, 2);
        d0 += __shfl_xor(d0, 4); d0 += __shfl_xor(d0, 8);
        d1 += __shfl_xor(d1, 1); d1 += __shfl_xor(d1, 2);
        d1 += __shfl_xor(d1, 4); d1 += __shfl_xor(d1, 8);
        d0 *= SCALE; d1 *= SCALE;
        if (j == 0) { sc[0][128] = d0; sc[1][128] = d1; }
        m0 = fmaxf(m0, d0); m1 = fmaxf(m1, d1);
    }
    m0 = fmaxf(m0, __shfl_xor(m0, 16)); m0 = fmaxf(m0, __shfl_xor(m0, 32));
    m1 = fmaxf(m1, __shfl_xor(m1, 16)); m1 = fmaxf(m1, __shfl_xor(m1, 32));
    if (lane == 0) { wm[0][w] = m0; wm[1][w] = m1; }
    __syncthreads();
    const float M0 = fmaxf(fmaxf(wm[0][0], wm[0][1]), fmaxf(wm[0][2], wm[0][3]));
    const float M1 = fmaxf(fmaxf(wm[1][0], wm[1][1]), fmaxf(wm[1][2], wm[1][3]));

    float4 o0 = {0,0,0,0}, o1 = {0,0,0,0};
    float l0 = 0.f, l1 = 0.f;
    #pragma unroll 4
    for (int i = 0; i < 8; ++i) {
        int r = rbase + i * 4 + sub;
        float4 vv = vst[r - s0][j];
        float p0 = __expf(sc[0][r - s0] - M0);
        float p1 = __expf(sc[1][r - s0] - M1);
        fma4(o0, p0, vv); fma4(o1, p1, vv);
        l0 += p0; l1 += p1;
    }
    if (c == 15 && w == 0 && sub == 0) {
        float p0 = __expf(sc[0][128] - M0);
        float p1 = __expf(sc[1][128] - M1);
        fma4(o0, p0, vnew); fma4(o1, p1, vnew);
        l0 += p0; l1 += p1;
    }
    o0.x += __shfl_xor(o0.x, 16); o0.x += __shfl_xor(o0.x, 32);
    o0.y += __shfl_xor(o0.y, 16); o0.y += __shfl_xor(o0.y, 32);
    o0.z += __shfl_xor(o0.z, 16); o0.z += __shfl_xor(o0.z, 32);
    o0.w += __shfl_xor(o0.w, 16); o0.w += __shfl_xor(o0.w, 32);
    o1.x += __shfl_xor(o1.x, 16); o1.x += __shfl_xor(o1.x, 32);
    o1.y += __shfl_xor(o1.y, 16); o1.y += __shfl_xor(o1.y, 32);
    o1.z += __shfl_xor(o1.z, 16); o1.z += __shfl_xor(o1.z, 32);
    o1.w += __shfl_xor(o1.w, 16); o1.w += __shfl_xor(o1.w, 32);
    l0 += __shfl_xor(l0, 16); l0 += __shfl_xor(l0, 32);
    l1 += __shfl_xor(l1, 16); l1 += __shfl_xor(l1, 32);
    if (sub == 0) {
        oacc[0][w][4*j+0] = o0.x; oacc[0][w][4*j+1] = o0.y;
        oacc[0][w][4*j+2] = o0.z; oacc[0][w][4*j+3] = o0.w;
        oacc[1][w][4*j+0] = o1.x; oacc[1][w][4*j+1] = o1.y;
        oacc[1][w][4*j+2] = o1.z; oacc[1][w][4*j+3] = o1.w;
    }
    if (lane == 0) { wl[0][w] = l0; wl[1][w] = l1; }
    __syncthreads();
    int pbase = WS_OPART + ((b * 8 + kvh) * 16 + c) * 132;
    if (tid < 128) {
        int h = tid >> 6, d = tid & 63;
        ws[pbase + h * 64 + d] = oacc[h][0][d] + oacc[h][1][d] + oacc[h][2][d] + oacc[h][3][d];
    } else if (tid == 128) {
        ws[pbase + 128] = M0;
        ws[pbase + 129] = wl[0][0] + wl[0][1] + wl[0][2] + wl[0][3];
        ws[pbase + 130] = M1;
        ws[pbase + 131] = wl[1][0] + wl[1][1] + wl[1][2] + wl[1][3];
    }
}

// ===== C: chunk-combine + O-proj GEMV (atomic into YO). grid 132 =====
__global__ __launch_bounds__(256) void k_c(const float* __restrict__ wo,
                                           float* __restrict__ ws, int l) {
    float4* ws4 = (float4*)ws;
    int tid = threadIdx.x, w = tid >> 6, lane = tid & 63;
    if (blockIdx.x >= 128) {            // zero YMLP
        float4 z = {0,0,0,0};
        ws4[(WS_YMLP >> 2) + (blockIdx.x - 128) * 256 + tid] = z;
        return;
    }
    __shared__ float xs[4][32];
    __shared__ float4 red[4][64][4];
    const int xt = blockIdx.x & 3, s = blockIdx.x >> 2;
    if (tid < 128) {
        const int bb = tid >> 5, rr = tid & 31;
        const int r = s * 32 + rr;
        const int kvh = r >> 7, g = (r >> 6) & 1, d = r & 63;
        const float* bp = ws + WS_OPART + (size_t)((bb * 8 + kvh) * 16) * 132;
        float m = -1e30f;
        #pragma unroll
        for (int cc = 0; cc < 16; ++cc)
            m = fmaxf(m, bp[cc * 132 + 128 + 2 * g]);
        float lt = 0.f, ot = 0.f;
        #pragma unroll
        for (int cc = 0; cc < 16; ++cc) {
            float f = __expf(bp[cc * 132 + 128 + 2 * g] - m);
            lt += bp[cc * 132 + 129 + 2 * g] * f;
            ot += bp[cc * 132 + g * 64 + d] * f;
        }
        xs[bb][rr] = ot / lt;
    }
    __syncthreads();
    const float4* W4 = (const float4*)(wo + (size_t)l * 1024 * 1024 + xt * 256 + lane * 4);
    float4 a0 = {0,0,0,0}, a1 = a0, a2 = a0, a3 = a0;
    #pragma unroll
    for (int rr = 0; rr < 8; ++rr) {
        int r = w * 8 + rr;
        float4 wv4 = W4[(size_t)(s * 32 + r) * 256];
        fma4(a0, xs[0][r], wv4); fma4(a1, xs[1][r], wv4);
        fma4(a2, xs[2][r], wv4); fma4(a3, xs[3][r], wv4);
    }
    red[w][lane][0] = a0; red[w][lane][1] = a1;
    red[w][lane][2] = a2; red[w][lane][3] = a3;
    __syncthreads();
    if (w == 0) {
        int c = xt * 256 + lane * 4;
        #pragma unroll
        for (int b = 0; b < 4; ++b) {
            float4 s0v = red[0][lane][b], s1v = red[1][lane][b],
                   s2v = red[2][lane][b], s3v = red[3][lane][b];
            s0v.x += s1v.x + s2v.x + s3v.x; s0v.y += s1v.y + s2v.y + s3v.y;
            s0v.z += s1v.z + s2v.z + s3v.z; s0v.w += s1v.w + s2v.w + s3v.w;
            atomicAdd(&ws[WS_YO + b * 1024 + c + 0], s0v.x);
            atomicAdd(&ws[WS_YO + b * 1024 + c + 1], s0v.y);
            atomicAdd(&ws[WS_YO + b * 1024 + c + 2], s0v.z);
            atomicAdd(&ws[WS_YO + b * 1024 + c + 3], s0v.w);
        }
    }
}

// ===== D: rms2 recompute + gate/up GEMV (k-split partials). grid (32,8) =====
__global__ __launch_bounds__(256) void k_d(const float* __restrict__ ln2,
                                           const float* __restrict__ wg,
                                           const float* __restrict__ wu,
                                           float* __restrict__ ws, int l) {
    float4* ws4 = (float4*)ws;
    int tid = threadIdx.x, w = tid >> 6, lane = tid & 63;
    __shared__ float xs[4][128];
    __shared__ float4 red[4][64][4];
    __shared__ float sred[4][4];
    const int mat = blockIdx.x >> 4, t16 = blockIdx.x & 15, y = blockIdx.y;

    float4 hn[4]; float ss[4];
    #pragma unroll
    for (int b = 0; b < 4; ++b) {
        float4 h = ws4[(WS_HB >> 2) + b * 256 + tid];
        float4 yv = ws4[(WS_YO >> 2) + b * 256 + tid];
        h.x = fmaf(MUP, yv.x, h.x); h.y = fmaf(MUP, yv.y, h.y);
        h.z = fmaf(MUP, yv.z, h.z); h.w = fmaf(MUP, yv.w, h.w);
        hn[b] = h;
        ss[b] = h.x*h.x + h.y*h.y + h.z*h.z + h.w*h.w;
    }
    #pragma unroll
    for (int b = 0; b < 4; ++b) {
        float v = wsum64(ss[b]);
        if (lane == 0) sred[w][b] = v;
    }
    __syncthreads();
    float rstd[4];
    #pragma unroll
    for (int b = 0; b < 4; ++b)
        rstd[b] = rsqrtf((sred[0][b] + sred[1][b] + sred[2][b] + sred[3][b]) * (1.f/1024.f) + EPS);
    if (blockIdx.x == 0 && blockIdx.y == 0) {
        #pragma unroll
        for (int b = 0; b < 4; ++b) ws4[(WS_HA >> 2) + b * 256 + tid] = hn[b];
    }
    {
        int tl = tid - y * 32;
        if (tl >= 0 && tl < 32) {
            float4 g4 = ((const float4*)ln2)[l * 256 + tid];
            #pragma unroll
            for (int b = 0; b < 4; ++b) {
                float4 xv;
                xv.x = hn[b].x * rstd[b] * g4.x; xv.y = hn[b].y * rstd[b] * g4.y;
                xv.z = hn[b].z * rstd[b] * g4.z; xv.w = hn[b].w * rstd[b] * g4.w;
                ((float4*)xs[b])[tl] = xv;
            }
        }
    }
    __syncthreads();

    const float* Wm = (mat ? wu : wg) + (size_t)l * 1024 * 4096;
    const float4* W4 = (const float4*)(Wm + t16 * 256 + lane * 4);
    float4 a0 = {0,0,0,0}, a1 = a0, a2 = a0, a3 = a0;
    #pragma unroll 8
    for (int rr = 0; rr < 32; ++rr) {
        int r = w * 32 + rr;
        float4 wv4 = W4[(size_t)(y * 128 + r) * 1024];
        fma4(a0, xs[0][r], wv4); fma4(a1, xs[1][r], wv4);
        fma4(a2, xs[2][r], wv4); fma4(a3, xs[3][r], wv4);
    }
    red[w][lane][0] = a0; red[w][lane][1] = a1;
    red[w][lane][2] = a2; red[w][lane][3] = a3;
    __syncthreads();
    if (w == 0) {
        float4* GUP4 = ws4 + (WS_GUP >> 2);
        #pragma unroll
        for (int b = 0; b < 4; ++b) {
            float4 s0v = red[0][lane][b], s1v = red[1][lane][b],
                   s2v = red[2][lane][b], s3v = red[3][lane][b];
            s0v.x += s1v.x + s2v.x + s3v.x; s0v.y += s1v.y + s2v.y + s3v.y;
            s0v.z += s1v.z + s2v.z + s3v.z; s0v.w += s1v.w + s2v.w + s3v.w;
            GUP4[(size_t)((mat * 8 + y) * 4 + b) * 1024 + t16 * 64 + lane] = s0v;
        }
    }
}

// ===== E: silu-combine + down GEMV (atomic into YMLP). grid (4,32) =====
__global__ __launch_bounds__(256) void k_e(const float* __restrict__ wd,
                                           float* __restrict__ ws, int l) {
    float4* ws4 = (float4*)ws;
    int tid = threadIdx.x, w = tid >> 6, lane = tid & 63;
    __shared__ float ts[4][128];
    __shared__ float4 red[4][64][4];
    const int xt = blockIdx.x, s = blockIdx.y;
    if (tid < 128) {
        const int bb = tid >> 5, i = tid & 31;
        const int f4 = s * 32 + i;
        const float4* GUP4 = (const float4*)ws4 + (WS_GUP >> 2);
        float4 g = {0,0,0,0}, u = {0,0,0,0};
        #pragma unroll
        for (int sp = 0; sp < 8; ++sp) {
            float4 gv = GUP4[(size_t)(sp * 4 + bb) * 1024 + f4];
            float4 uv = GUP4[(size_t)((8 + sp) * 4 + bb) * 1024 + f4];
            g.x += gv.x; g.y += gv.y; g.z += gv.z; g.w += gv.w;
            u.x += uv.x; u.y += uv.y; u.z += uv.z; u.w += uv.w;
        }
        float4 t;
        t.x = (g.x / (1.f + __expf(-g.x))) * u.x;
        t.y = (g.y / (1.f + __expf(-g.y))) * u.y;
        t.z = (g.z / (1.f + __expf(-g.z))) * u.z;
        t.w = (g.w / (1.f + __expf(-g.w))) * u.w;
        ((float4*)ts[bb])[i] = t;
    }
    __syncthreads();
    const float4* W4 = (const float4*)(wd + (size_t)l * 4096 * 1024 + xt * 256 + lane * 4);
    float4 a0 = {0,0,0,0}, a1 = a0, a2 = a0, a3 = a0;
    #pragma unroll 8
    for (int rr = 0; rr < 32; ++rr) {
        int r = w * 32 + rr;
        float4 wv4 = W4[(size_t)(s * 128 + r) * 256];
        fma4(a0, ts[0][r], wv4); fma4(a1, ts[1][r], wv4);
        fma4(a2, ts[2][r], wv4); fma4(a3, ts[3][r], wv4);
    }
    red[w][lane][0] = a0; red[w][lane][1] = a1;
    red[w][lane][2] = a2; red[w][lane][3] = a3;
    __syncthreads();
    if (w == 0) {
        int c = xt * 256 + lane * 4;
        #pragma unroll
        for (int b = 0; b < 4; ++b) {
            float4 s0v = red[0][lane][b], s1v = red[1][lane][b],
                   s2v = red[2][lane][b], s3v = red[3][lane][b];
            s0v.x += s1v.x + s2v.x + s3v.x; s0v.y += s1v.y + s2v.y + s3v.y;
            s0v.z += s1v.z + s2v.z + s3v.z; s0v.w += s1v.w + s2v.w + s3v.w;
            atomicAdd(&ws[WS_YMLP + b * 1024 + c + 0], s0v.x);
            atomicAdd(&ws[WS_YMLP + b * 1024 + c + 1], s0v.y);
            atomicAdd(&ws[WS_YMLP + b * 1024 + c + 2], s0v.z);
            atomicAdd(&ws[WS_YMLP + b * 1024 + c + 3], s0v.w);
        }
    }
}

__global__ __launch_bounds__(256) void k_final(const float* __restrict__ normw,
                                               float* __restrict__ ws,
                                               float* __restrict__ out) {
    float4* ws4 = (float4*)ws;
    int tid = threadIdx.x;
    int b = blockIdx.x, w = tid >> 6, lane = tid & 63;
    __shared__ float sred[4];
    float4 h = ws4[(WS_HA >> 2) + b * 256 + tid];
    float4 y = ws4[(WS_YMLP >> 2) + b * 256 + tid];
    h.x = fmaf(MUP, y.x, h.x); h.y = fmaf(MUP, y.y, h.y);
    h.z = fmaf(MUP, y.z, h.z); h.w = fmaf(MUP, y.w, h.w);
    float ssv = h.x*h.x + h.y*h.y + h.z*h.z + h.w*h.w;
    float v = wsum64(ssv);
    if (lane == 0) sred[w] = v;
    __syncthreads();
    float rstd = rsqrtf((sred[0] + sred[1] + sred[2] + sred[3]) * (1.f/1024.f) + EPS);
    float4 g4 = ((const float4*)normw)[tid];
    float4 o;
    o.x = h.x * rstd * g4.x; o.y = h.y * rstd * g4.y;
    o.z = h.z * rstd * g4.z; o.w = h.w * rstd * g4.w;
    ((float4*)out)[b * 256 + tid] = o;
}

extern "C" void kernel_launch(void* const* d_in, const int* in_sizes, int n_in,
                              void* d_out, int out_size, void* d_ws, size_t ws_size,
                              hipStream_t stream) {
    const float* emb  = (const float*)d_in[0];
    const float* kc   = (const float*)d_in[1];
    const float* vc   = (const float*)d_in[2];
    const float* ln1  = (const float*)d_in[3];
    const float* ln2  = (const float*)d_in[4];
    const float* nrmw = (const float*)d_in[5];
    const float* wq   = (const float*)d_in[6];
    const float* wk   = (const float*)d_in[7];
    const float* wv   = (const float*)d_in[8];
    const float* wo   = (const float*)d_in[9];
    const float* wg   = (const float*)d_in[10];
    const float* wu   = (const float*)d_in[11];
    const float* wd   = (const float*)d_in[12];
    const int*   cl   = (const int*)d_in[13];

    float* out = (float*)d_out;
    float* ws  = (float*)d_ws;
    float* nk  = out + OUT_NK;
    float* nv  = out + OUT_NV;

    k_init<<<3, 256, 0, stream>>>(emb, cl, ws, out);
    for (int l = 0; l < 16; ++l) {
        k_a<<<260, 256, 0, stream>>>(ln1, wq, wk, wv, ws, l);
        k_b<<<512, 256, 0, stream>>>(kc, vc, cl, ws, nk, nv, l);
        k_c<<<132, 256, 0, stream>>>(wo, ws, l);
        k_d<<<dim3(32, 8), 256, 0, stream>>>(ln2, wg, wu, ws, l);
        k_e<<<dim3(4, 32), 256, 0, stream>>>(wd, ws, l);
    }
    k_final<<<4, 256, 0, stream>>>(nrmw, ws, out);
}